// Round 1
// baseline (167.159 us; speedup 1.0000x reference)
//
#include <hip/hip_runtime.h>

#define C_CH   1024
#define T_DIM  16384
#define NSTEPS (T_DIM - 16)   // 16368
#define PAD    8
#define TP     (T_DIM + 16)   // padded time length 16400
#define CHUNK  512
#define NCHUNK 32             // 32*512 = 16384 >= 16368
#define WARM   256

// ws layout:
//   [0, 8*T_DIM*sizeof(double))  : double partial[8][T_DIM]   (1 MiB)
//   [1 MiB, +TP*4)               : float  colmean[TP]
#define WS_CM_OFFSET (8u * T_DIM * sizeof(double))

// ---------------- Kernel 1: per-row-chunk column partial sums ----------------
__global__ void colsum_partial(const float* __restrict__ inp, double* __restrict__ part) {
    int col = blockIdx.x * 256 + threadIdx.x;   // 0..16383
    int rc  = blockIdx.y;                       // 0..7 (row chunk of 128)
    const float* p = inp + (size_t)rc * 128 * T_DIM + col;
    double acc = 0.0;
    #pragma unroll 4
    for (int r = 0; r < 128; ++r) acc += (double)p[(size_t)r * T_DIM];
    part[(size_t)rc * T_DIM + col] = acc;
}

// ---------------- Kernel 2: reduce partials -> padded column means ----------------
__global__ void colmean_reduce(const double* __restrict__ part, float* __restrict__ cm) {
    int s = blockIdx.x * 256 + threadIdx.x;     // padded index 0..TP-1
    if (s >= TP) return;
    float v = 0.0f;
    if (s >= PAD && s < T_DIM + PAD) {
        int col = s - PAD;
        double t = 0.0;
        #pragma unroll
        for (int r = 0; r < 8; ++r) t += part[(size_t)r * T_DIM + col];
        v = (float)(t * (1.0 / 1024.0));        // /1024 is exact
    }
    cm[s] = v;
}

// ---------------- Kernel 3: time-chunk-parallel per-channel scan ----------------
__global__ __launch_bounds__(64) void scan_kernel(const float* __restrict__ inp,
                                                  const float* __restrict__ cm,
                                                  float* __restrict__ out) {
    const int k  = blockIdx.x;                      // time chunk 0..NCHUNK-1
    const int c  = blockIdx.y * 64 + threadIdx.x;   // channel
    const int t0 = k * CHUNK;
    const int tend = min(t0 + CHUNK, NSTEPS);       // chunk 31: 496 steps (mult of 16)
    const int tw = (k == 0) ? 0 : t0 - WARM;        // warmup start (mult of 16)

    const float* row  = inp + (size_t)c * T_DIM;
    float*       orow = out + (size_t)c * T_DIM;

    // window registers: xs = inp_padded[c, tw..tw+15], ms = colmean[tw..tw+15]
    float xs[16], ms[16];
    double win = 0.0;
    #pragma unroll
    for (int j = 0; j < 16; ++j) {
        int s = tw + j;
        float x = (s >= PAD) ? row[s - PAD] : 0.0f;  // right pad never touched here
        float m = cm[s];
        xs[j] = x; ms[j] = m;
        win += (double)(x * m);
    }

    float w = 1.0f, mem = 0.0f;   // exact for k==0; speculative (warmup-converged) otherwise

    for (int t = tw; t < tend; t += 16) {
        // incoming window elements: padded positions t+16..t+31 -> row idx t+8..t+23 (always valid)
        float4 a0 = *(const float4*)(row + t + 8);
        float4 a1 = *(const float4*)(row + t + 12);
        float4 a2 = *(const float4*)(row + t + 16);
        float4 a3 = *(const float4*)(row + t + 20);
        float4 b0 = *(const float4*)(cm + t + 16);
        float4 b1 = *(const float4*)(cm + t + 20);
        float4 b2 = *(const float4*)(cm + t + 24);
        float4 b3 = *(const float4*)(cm + t + 28);
        float xn[16] = {a0.x,a0.y,a0.z,a0.w, a1.x,a1.y,a1.z,a1.w,
                        a2.x,a2.y,a2.z,a2.w, a3.x,a3.y,a3.z,a3.w};
        float mn[16] = {b0.x,b0.y,b0.z,b0.w, b1.x,b1.y,b1.z,b1.w,
                        b2.x,b2.y,b2.z,b2.w, b3.x,b3.y,b3.z,b3.w};
        float spk[16];

        #pragma unroll
        for (int j = 0; j < 16; ++j) {
            // window is [t+j, t+j+15]; B_ram = its product-sum
            float B = (float)win;
            w = fminf(fmaxf(fmaf(0.5f, w, 0.5f * B), -1.0f), 3.0f);
            float x = xs[j];                         // inp_padded[c, t+j]
            float r = (mem > 1.0f) ? 1.0f : 0.0f;    // reset from previous mem
            mem = fmaf(0.95f, mem, fmaf(w, x, -r));
            spk[j] = (mem > 1.0f) ? 1.0f : 0.0f;
            // slide window: drop q(t+j), add q(t+j+16); accumulate in double (no drift)
            win += (double)(xn[j] * mn[j]) - (double)(x * ms[j]);
            xs[j] = xn[j]; ms[j] = mn[j];
        }

        if (t >= t0) {   // uniform: warmup blocks skipped entirely
            *(float4*)(orow + t)      = make_float4(spk[0],  spk[1],  spk[2],  spk[3]);
            *(float4*)(orow + t + 4)  = make_float4(spk[4],  spk[5],  spk[6],  spk[7]);
            *(float4*)(orow + t + 8)  = make_float4(spk[8],  spk[9],  spk[10], spk[11]);
            *(float4*)(orow + t + 12) = make_float4(spk[12], spk[13], spk[14], spk[15]);
        }
    }
}

// ---------------- Kernel 4: copy the untouched tail columns ----------------
__global__ void tail_copy(const float* __restrict__ inp, float* __restrict__ out) {
    int i = blockIdx.x * 256 + threadIdx.x;   // 0..16383
    int c = i >> 4, j = i & 15;
    size_t idx = (size_t)c * T_DIM + NSTEPS + j;
    out[idx] = inp[idx];
}

extern "C" void kernel_launch(void* const* d_in, const int* in_sizes, int n_in,
                              void* d_out, int out_size, void* d_ws, size_t ws_size,
                              hipStream_t stream) {
    const float* inp = (const float*)d_in[0];
    float* out = (float*)d_out;
    double* part = (double*)d_ws;
    float* cm = (float*)((char*)d_ws + WS_CM_OFFSET);

    colsum_partial<<<dim3(T_DIM / 256, 8), 256, 0, stream>>>(inp, part);
    colmean_reduce<<<dim3((TP + 255) / 256), 256, 0, stream>>>(part, cm);
    scan_kernel<<<dim3(NCHUNK, C_CH / 64), 64, 0, stream>>>(inp, cm, out);
    tail_copy<<<dim3(64), 256, 0, stream>>>(inp, out);
}

// Round 2
// 154.822 us; speedup vs baseline: 1.0797x; 1.0797x over previous
//
#include <hip/hip_runtime.h>

#define C_CH   1024
#define T_DIM  16384
#define NSTEPS (T_DIM - 16)   // 16368
#define PAD    8
#define TP     (T_DIM + 16)   // padded time length 16400
#define CHUNK  256
#define NCHUNK 64             // 64*256 = 16384 >= 16368
#define WARM   256

// ws layout:
//   [0, 8*T_DIM*sizeof(double))  : double partial[8][T_DIM]   (1 MiB)
//   [1 MiB, +TP*4)               : float  colmean[TP]
#define WS_CM_OFFSET (8u * T_DIM * sizeof(double))

// ---------------- Kernel 1: per-row-chunk column partial sums (float4) ----------------
__global__ void colsum_partial(const float* __restrict__ inp, double* __restrict__ part) {
    int col4 = (blockIdx.x * 256 + threadIdx.x) * 4;   // 0..16380 step 4
    int rc   = blockIdx.y;                             // 0..7 (row chunk of 128)
    const float* p = inp + (size_t)rc * 128 * T_DIM + col4;
    double ax = 0.0, ay = 0.0, az = 0.0, aw = 0.0;
    #pragma unroll 4
    for (int r = 0; r < 128; ++r) {
        float4 v = *(const float4*)(p + (size_t)r * T_DIM);
        ax += (double)v.x; ay += (double)v.y; az += (double)v.z; aw += (double)v.w;
    }
    double* q = part + (size_t)rc * T_DIM + col4;
    q[0] = ax; q[1] = ay; q[2] = az; q[3] = aw;
}

// ---------------- Kernel 2: reduce partials -> padded column means, + tail copy ----------------
__global__ void colmean_tail(const double* __restrict__ part, const float* __restrict__ inp,
                             float* __restrict__ cm, float* __restrict__ out) {
    int i = blockIdx.x * 256 + threadIdx.x;   // 0..16639
    if (i < TP) {
        float v = 0.0f;
        if (i >= PAD && i < T_DIM + PAD) {
            int col = i - PAD;
            double t = 0.0;
            #pragma unroll
            for (int r = 0; r < 8; ++r) t += part[(size_t)r * T_DIM + col];
            v = (float)(t * (1.0 / 1024.0));        // /1024 is exact
        }
        cm[i] = v;
    }
    if (i < C_CH * 16) {                       // tail columns NSTEPS..T_DIM-1
        int c = i >> 4, j = i & 15;
        size_t idx = (size_t)c * T_DIM + NSTEPS + j;
        out[idx] = inp[idx];
    }
}

// ---------------- Kernel 3: time-chunk-parallel per-channel scan (pipelined) ----------------
__global__ __launch_bounds__(64) void scan_kernel(const float* __restrict__ inp,
                                                  const float* __restrict__ cm,
                                                  float* __restrict__ out) {
    const int k  = blockIdx.x;                      // time chunk 0..NCHUNK-1
    const int c  = blockIdx.y * 64 + threadIdx.x;   // channel
    const int t0 = k * CHUNK;
    const int tend = min(t0 + CHUNK, NSTEPS);       // last chunk: 240 steps (mult of 16)
    const int tw = (k == 0) ? 0 : t0 - WARM;        // warmup start (mult of 16)

    const float* row  = inp + (size_t)c * T_DIM;
    float*       orow = out + (size_t)c * T_DIM;

    // window registers: xs = inp_padded[c, tw..tw+15], ms = colmean[tw..tw+15]
    float xs[16], ms[16];
    float win = 0.0f;   // per-chunk accumulation <= 784 steps -> fp32 drift ~5e-7, safe
    #pragma unroll
    for (int j = 0; j < 16; ++j) {
        int s = tw + j;
        float x = (s >= PAD) ? row[s - PAD] : 0.0f;
        float m = cm[s];
        xs[j] = x; ms[j] = m;
        win = fmaf(x, m, win);
    }

    float w = 1.0f, mem = 0.0f;   // exact for k==0; warmup-converged otherwise

    // preload iteration tw's incoming data
    float4 a0 = *(const float4*)(row + tw + 8);
    float4 a1 = *(const float4*)(row + tw + 12);
    float4 a2 = *(const float4*)(row + tw + 16);
    float4 a3 = *(const float4*)(row + tw + 20);
    float4 b0 = *(const float4*)(cm + tw + 16);
    float4 b1 = *(const float4*)(cm + tw + 20);
    float4 b2 = *(const float4*)(cm + tw + 24);
    float4 b3 = *(const float4*)(cm + tw + 28);

    for (int t = tw; t < tend; t += 16) {
        float xn[16] = {a0.x,a0.y,a0.z,a0.w, a1.x,a1.y,a1.z,a1.w,
                        a2.x,a2.y,a2.z,a2.w, a3.x,a3.y,a3.z,a3.w};
        float mn[16] = {b0.x,b0.y,b0.z,b0.w, b1.x,b1.y,b1.z,b1.w,
                        b2.x,b2.y,b2.z,b2.w, b3.x,b3.y,b3.z,b3.w};

        // issue next iteration's loads now (clamped on last iter to stay in-bounds)
        int ts = (t + 16 < tend) ? (t + 16) : t;
        a0 = *(const float4*)(row + ts + 8);
        a1 = *(const float4*)(row + ts + 12);
        a2 = *(const float4*)(row + ts + 16);
        a3 = *(const float4*)(row + ts + 20);
        b0 = *(const float4*)(cm + ts + 16);
        b1 = *(const float4*)(cm + ts + 20);
        b2 = *(const float4*)(cm + ts + 24);
        b3 = *(const float4*)(cm + ts + 28);

        float spk[16];
        #pragma unroll
        for (int j = 0; j < 16; ++j) {
            // window is [t+j, t+j+15]; B_ram = its product-sum
            w = fminf(fmaxf(fmaf(0.5f, w, 0.5f * win), -1.0f), 3.0f);
            float x = xs[j];                         // inp_padded[c, t+j]
            float r = (mem > 1.0f) ? 1.0f : 0.0f;    // reset from previous mem
            mem = fmaf(0.95f, mem, fmaf(w, x, -r));
            spk[j] = (mem > 1.0f) ? 1.0f : 0.0f;
            // slide window: drop q(t+j), add q(t+j+16)
            win = fmaf(xn[j], mn[j], fmaf(-x, ms[j], win));
            xs[j] = xn[j]; ms[j] = mn[j];
        }

        if (t >= t0) {   // wave-uniform: warmup blocks skipped entirely
            *(float4*)(orow + t)      = make_float4(spk[0],  spk[1],  spk[2],  spk[3]);
            *(float4*)(orow + t + 4)  = make_float4(spk[4],  spk[5],  spk[6],  spk[7]);
            *(float4*)(orow + t + 8)  = make_float4(spk[8],  spk[9],  spk[10], spk[11]);
            *(float4*)(orow + t + 12) = make_float4(spk[12], spk[13], spk[14], spk[15]);
        }
    }
}

extern "C" void kernel_launch(void* const* d_in, const int* in_sizes, int n_in,
                              void* d_out, int out_size, void* d_ws, size_t ws_size,
                              hipStream_t stream) {
    const float* inp = (const float*)d_in[0];
    float* out = (float*)d_out;
    double* part = (double*)d_ws;
    float* cm = (float*)((char*)d_ws + WS_CM_OFFSET);

    colsum_partial<<<dim3(T_DIM / 1024, 8), 256, 0, stream>>>(inp, part);
    colmean_tail<<<dim3(65), 256, 0, stream>>>(part, inp, cm, out);
    scan_kernel<<<dim3(NCHUNK, C_CH / 64), 64, 0, stream>>>(inp, cm, out);
}